// Round 1
// baseline (47.313 us; speedup 1.0000x reference)
//
#include <hip/hip_runtime.h>
#include <hip/hip_bf16.h>

#define NUM_B 64
#define SEQ_T 2048
#define DIM_D 256
#define BLOCKS_PER_BATCH 32                       // 2048 rows / 32 = 64 rows/block
#define ROWS_PER_BLOCK (SEQ_T / BLOCKS_PER_BATCH) // 64
#define WAVES_PER_BLOCK 4
#define ROWS_PER_WAVE (ROWS_PER_BLOCK / WAVES_PER_BLOCK) // 16

__global__ __launch_bounds__(256) void stocklora_kernel(
    const float* __restrict__ latent,   // [B, T, D]
    const int*   __restrict__ idx,      // [B]
    const float* __restrict__ embedA,   // [NUM_STOCKS, D*2], A[d,r]=flat[d*2+r]
    const float* __restrict__ embedB,   // [NUM_STOCKS, D*2]
    const float* __restrict__ beta,     // [NUM_STOCKS, D]
    float*       __restrict__ out)      // [B, T, D]
{
    const int block = blockIdx.x;
    const int batch = block / BLOCKS_PER_BATCH;
    const int seg   = block % BLOCKS_PER_BATCH;
    const int wave  = threadIdx.x >> 6;
    const int lane  = threadIdx.x & 63;

    const int stock = idx[batch];

    // Lane l owns d0 = 4*l .. 4*l+3.
    // A fragment: flat[8l .. 8l+7] = {A[d0,0],A[d0,1],A[d0+1,0],A[d0+1,1],
    //                                 A[d0+2,0],A[d0+2,1],A[d0+3,0],A[d0+3,1]}
    const float4* A4 = (const float4*)(embedA + (size_t)stock * (DIM_D * 2));
    const float4* B4 = (const float4*)(embedB + (size_t)stock * (DIM_D * 2));
    const float4 a_lo = A4[lane * 2];
    const float4 a_hi = A4[lane * 2 + 1];
    const float4 b_lo = B4[lane * 2];
    const float4 b_hi = B4[lane * 2 + 1];
    const float4 bet  = ((const float4*)(beta + (size_t)stock * DIM_D))[lane];

    const int row0 = seg * ROWS_PER_BLOCK + wave * ROWS_PER_WAVE;
    const float* lat  = latent + (size_t)batch * SEQ_T * DIM_D;
    float*       outp = out    + (size_t)batch * SEQ_T * DIM_D;

    #pragma unroll 4
    for (int r = 0; r < ROWS_PER_WAVE; ++r) {
        const int row = row0 + r;
        const float4 x = ((const float4*)(lat + (size_t)row * DIM_D))[lane];

        // Per-lane partial dot products for the two rank components.
        float p0 = x.x * a_lo.x + x.y * a_lo.z + x.z * a_hi.x + x.w * a_hi.z;
        float p1 = x.x * a_lo.y + x.y * a_lo.w + x.z * a_hi.y + x.w * a_hi.w;

        // 64-lane butterfly reduction.
        #pragma unroll
        for (int m = 1; m < 64; m <<= 1) {
            p0 += __shfl_xor(p0, m, 64);
            p1 += __shfl_xor(p1, m, 64);
        }

        float4 o;
        o.x = p0 * b_lo.x + p1 * b_lo.y + bet.x;
        o.y = p0 * b_lo.z + p1 * b_lo.w + bet.y;
        o.z = p0 * b_hi.x + p1 * b_hi.y + bet.z;
        o.w = p0 * b_hi.z + p1 * b_hi.w + bet.w;
        ((float4*)(outp + (size_t)row * DIM_D))[lane] = o;
    }
}

extern "C" void kernel_launch(void* const* d_in, const int* in_sizes, int n_in,
                              void* d_out, int out_size, void* d_ws, size_t ws_size,
                              hipStream_t stream) {
    const float* latent = (const float*)d_in[0];
    const int*   idx    = (const int*)d_in[1];
    const float* embedA = (const float*)d_in[2];
    const float* embedB = (const float*)d_in[3];
    const float* beta   = (const float*)d_in[4];
    float* out = (float*)d_out;

    dim3 grid(NUM_B * BLOCKS_PER_BATCH);
    dim3 block(256);
    stocklora_kernel<<<grid, block, 0, stream>>>(latent, idx, embedA, embedB, beta, out);
}

// Round 4
// 45.421 us; speedup vs baseline: 1.0417x; 1.0417x over previous
//
#include <hip/hip_runtime.h>
#include <hip/hip_bf16.h>

#define NUM_B 64
#define SEQ_T 2048
#define DIM_D 256
#define BLOCKS_PER_BATCH 32                       // 2048 rows / 32 = 64 rows/block
#define ROWS_PER_BLOCK (SEQ_T / BLOCKS_PER_BATCH) // 64
#define WAVES_PER_BLOCK 4
#define ROWS_PER_WAVE (ROWS_PER_BLOCK / WAVES_PER_BLOCK) // 16

typedef float nfloat4 __attribute__((ext_vector_type(4)));  // native vec for nt-store

__global__ __launch_bounds__(256) void stocklora_kernel(
    const float* __restrict__ latent,   // [B, T, D]
    const int*   __restrict__ idx,      // [B]
    const float* __restrict__ embedA,   // [NUM_STOCKS, D*2], A[d,r]=flat[d*2+r]
    const float* __restrict__ embedB,   // [NUM_STOCKS, D*2]
    const float* __restrict__ beta,     // [NUM_STOCKS, D]
    float*       __restrict__ out)      // [B, T, D]
{
    const int block = blockIdx.x;
    const int batch = block / BLOCKS_PER_BATCH;
    const int seg   = block % BLOCKS_PER_BATCH;
    const int wave  = threadIdx.x >> 6;
    const int lane  = threadIdx.x & 63;

    const int stock = idx[batch];

    // Lane l owns d0 = 4*l .. 4*l+3.
    const float4* A4 = (const float4*)(embedA + (size_t)stock * (DIM_D * 2));
    const float4* B4 = (const float4*)(embedB + (size_t)stock * (DIM_D * 2));
    const float4 a_lo = A4[lane * 2];
    const float4 a_hi = A4[lane * 2 + 1];
    const float4 b_lo = B4[lane * 2];
    const float4 b_hi = B4[lane * 2 + 1];
    const float4 bet  = ((const float4*)(beta + (size_t)stock * DIM_D))[lane];

    const int row0 = seg * ROWS_PER_BLOCK + wave * ROWS_PER_WAVE;
    const float* lat  = latent + (size_t)batch * SEQ_T * DIM_D;
    float*       outp = out    + (size_t)batch * SEQ_T * DIM_D;

    #pragma unroll 4
    for (int r = 0; r < ROWS_PER_WAVE; ++r) {
        const int row = row0 + r;
        const float4 x = ((const float4*)(lat + (size_t)row * DIM_D))[lane];

        // Per-lane partial dot products for the two rank components.
        float p0 = x.x * a_lo.x + x.y * a_lo.z + x.z * a_hi.x + x.w * a_hi.z;
        float p1 = x.x * a_lo.y + x.y * a_lo.w + x.z * a_hi.y + x.w * a_hi.w;

        // 64-lane butterfly reduction.
        #pragma unroll
        for (int m = 1; m < 64; m <<= 1) {
            p0 += __shfl_xor(p0, m, 64);
            p1 += __shfl_xor(p1, m, 64);
        }

        nfloat4 o;
        o.x = p0 * b_lo.x + p1 * b_lo.y + bet.x;
        o.y = p0 * b_lo.z + p1 * b_lo.w + bet.y;
        o.z = p0 * b_hi.x + p1 * b_hi.y + bet.z;
        o.w = p0 * b_hi.z + p1 * b_hi.w + bet.w;

        // Output is write-once / never re-read: non-temporal store keeps it
        // from evicting latent out of the 256 MiB Infinity Cache.
        nfloat4* dst = ((nfloat4*)(outp + (size_t)row * DIM_D)) + lane;
        __builtin_nontemporal_store(o, dst);
    }
}

extern "C" void kernel_launch(void* const* d_in, const int* in_sizes, int n_in,
                              void* d_out, int out_size, void* d_ws, size_t ws_size,
                              hipStream_t stream) {
    const float* latent = (const float*)d_in[0];
    const int*   idx    = (const int*)d_in[1];
    const float* embedA = (const float*)d_in[2];
    const float* embedB = (const float*)d_in[3];
    const float* beta   = (const float*)d_in[4];
    float* out = (float*)d_out;

    dim3 grid(NUM_B * BLOCKS_PER_BATCH);
    dim3 block(256);
    stocklora_kernel<<<grid, block, 0, stream>>>(latent, idx, embedA, embedB, beta, out);
}